// Round 1
// baseline (1017.789 us; speedup 1.0000x reference)
//
#include <hip/hip_runtime.h>
#include <hip/hip_bf16.h>
#include <math.h>

#define C_CLASSES 100000
#define D_DIM     128
#define DEPTH     8
#define B_BATCH   2048
#define NBLK_N    782              // ceil(100000/128)
#define C_PAD     (NBLK_N*128)     // 100096

typedef __bf16 bf16;
typedef __bf16 bf16x8 __attribute__((ext_vector_type(8)));
typedef float  f32x4  __attribute__((ext_vector_type(4)));

// ---------------- K0: cast x to bf16 ----------------
__global__ __launch_bounds__(256)
void k_cast_x(const float* __restrict__ x, bf16* __restrict__ xb, int n) {
    int i = blockIdx.x * 256 + threadIdx.x;
    if (i < n) xb[i] = (bf16)x[i];
}

// ---------------- K1: gather tree-path rows, sum, cast to bf16 ----------------
// 2 classes per 256-thread block; rows [C, C_PAD) zero-filled.
__global__ __launch_bounds__(256)
void k_gather_aw(const float* __restrict__ w, const int* __restrict__ pidx,
                 bf16* __restrict__ aw) {
    int c = blockIdx.x * 2 + (threadIdx.x >> 7);
    int d = threadIdx.x & 127;
    if (c >= C_PAD) return;
    float acc = 0.f;
    if (c < C_CLASSES) {
#pragma unroll
        for (int j = 0; j < DEPTH; ++j) {
            int r = pidx[c * DEPTH + j];
            acc += w[(size_t)r * D_DIM + d];
        }
    }
    aw[(size_t)c * D_DIM + d] = (bf16)acc;
}

// ---------------- K2: bf16 MFMA GEMM + fused exp-rowsum epilogue ----------------
// logits[m][n] = sum_k xb[m][k] * aw[n][k]   (NT gemm, both operands K-contiguous)
// 128x128 tile / block, 4 waves, each wave 64x64 via 4x4 grid of 16x16x32 frags.
// LDS: 2 x 32KB, XOR swizzle on 16B granules (g' = g ^ (row & 15)) -> <=2-way banks (free).
__global__ __launch_bounds__(256, 2)
void k_gemm(const bf16* __restrict__ xb, const bf16* __restrict__ aw,
            float* __restrict__ logits, float* __restrict__ partial) {
    __shared__ uint4 As4[128 * 16];   // 32 KB
    __shared__ uint4 Bs4[128 * 16];   // 32 KB
    const int tid = threadIdx.x;
    const int bm = blockIdx.x, bn = blockIdx.y;
    const uint4* xbv = (const uint4*)xb;
    const uint4* awv = (const uint4*)aw;

    // stage A (x rows) and B (aw rows), full K=128 at once
#pragma unroll
    for (int it = 0; it < 8; ++it) {
        int G = it * 256 + tid;
        int m = G >> 4, g = G & 15;
        As4[m * 16 + (g ^ (m & 15))] = xbv[(size_t)(bm * 128 + m) * 16 + g];
    }
#pragma unroll
    for (int it = 0; it < 8; ++it) {
        int G = it * 256 + tid;
        int m = G >> 4, g = G & 15;
        Bs4[m * 16 + (g ^ (m & 15))] = awv[(size_t)(bn * 128 + m) * 16 + g];
    }
    __syncthreads();

    const int lane = tid & 63, w = tid >> 6;
    const int wm = (w >> 1) * 64, wn = (w & 1) * 64;
    const int quad = lane >> 4, l15 = lane & 15;
    const bf16x8* Asv = (const bf16x8*)As4;
    const bf16x8* Bsv = (const bf16x8*)Bs4;

    f32x4 acc[4][4];
#pragma unroll
    for (int ti = 0; ti < 4; ++ti)
#pragma unroll
        for (int tj = 0; tj < 4; ++tj)
            acc[ti][tj] = (f32x4){0.f, 0.f, 0.f, 0.f};

#pragma unroll
    for (int ks = 0; ks < 4; ++ks) {
        const int gsw = (ks * 4 + quad) ^ l15;   // swizzled granule (row&15 == l15)
        bf16x8 af[4], bfr[4];
#pragma unroll
        for (int ti = 0; ti < 4; ++ti) af[ti] = Asv[(wm + ti * 16 + l15) * 16 + gsw];
#pragma unroll
        for (int tj = 0; tj < 4; ++tj) bfr[tj] = Bsv[(wn + tj * 16 + l15) * 16 + gsw];
#pragma unroll
        for (int ti = 0; ti < 4; ++ti)
#pragma unroll
            for (int tj = 0; tj < 4; ++tj)
                acc[ti][tj] = __builtin_amdgcn_mfma_f32_16x16x32_bf16(
                    af[ti], bfr[tj], acc[ti][tj], 0, 0, 0);
    }
    __syncthreads();           // done reading As -> reuse as reduction buffer

    float* red = (float*)As4;  // 256 floats: [2][128] (col-half, row_local)
    red[tid] = 0.f;
    __syncthreads();

    const long col0 = (long)bn * 128 + wn;
    const int  row0 = bm * 128 + wm;
#pragma unroll
    for (int ti = 0; ti < 4; ++ti) {
#pragma unroll
        for (int i = 0; i < 4; ++i) {
            const int row = row0 + ti * 16 + quad * 4 + i;   // C/D: row=(lane>>4)*4+reg
            float rs = 0.f;
#pragma unroll
            for (int tj = 0; tj < 4; ++tj) {
                long col = col0 + tj * 16 + l15;             // C/D: col=lane&15
                float v = acc[ti][tj][i];
                if (col < C_CLASSES) {
                    logits[(long)row * C_CLASSES + col] = v;
                    rs += __expf(v);
                }
            }
            rs += __shfl_xor(rs, 1);
            rs += __shfl_xor(rs, 2);
            rs += __shfl_xor(rs, 4);
            rs += __shfl_xor(rs, 8);
            if (l15 == 0) red[(w & 1) * 128 + wm + ti * 16 + quad * 4 + i] = rs;
        }
    }
    __syncthreads();
    if (tid < 128)
        partial[(size_t)(bm * 128 + tid) * NBLK_N + bn] = red[tid] + red[128 + tid];
}

// ---------------- K3: per-row logsumexp - logit_y ----------------
__global__ __launch_bounds__(256)
void k_row_reduce(const float* __restrict__ partial, const float* __restrict__ logits,
                  const int* __restrict__ y, float* __restrict__ contrib) {
    const int b = blockIdx.x, tid = threadIdx.x;
    float s = 0.f;
    for (int j = tid; j < NBLK_N; j += 256) s += partial[(size_t)b * NBLK_N + j];
#pragma unroll
    for (int m = 1; m < 64; m <<= 1) s += __shfl_xor(s, m);
    __shared__ float sm[4];
    if ((tid & 63) == 0) sm[tid >> 6] = s;
    __syncthreads();
    if (tid == 0) {
        float t = sm[0] + sm[1] + sm[2] + sm[3];
        float lse = logf(t);
        float ly = logits[(size_t)b * C_CLASSES + y[b]];
        contrib[b] = lse - ly;
    }
}

// ---------------- K4: mean over batch -> loss ----------------
__global__ __launch_bounds__(256)
void k_loss(const float* __restrict__ contrib, float* __restrict__ out) {
    const int tid = threadIdx.x;
    float s = 0.f;
#pragma unroll
    for (int k = 0; k < 8; ++k) s += contrib[tid + k * 256];
#pragma unroll
    for (int m = 1; m < 64; m <<= 1) s += __shfl_xor(s, m);
    __shared__ float sm[4];
    if ((tid & 63) == 0) sm[tid >> 6] = s;
    __syncthreads();
    if (tid == 0) out[0] = (sm[0] + sm[1] + sm[2] + sm[3]) * (1.0f / B_BATCH);
}

extern "C" void kernel_launch(void* const* d_in, const int* in_sizes, int n_in,
                              void* d_out, int out_size, void* d_ws, size_t ws_size,
                              hipStream_t stream) {
    const float* x    = (const float*)d_in[0];
    const int*   y    = (const int*)d_in[1];
    const float* w    = (const float*)d_in[2];
    const int*   pidx = (const int*)d_in[3];
    float* out = (float*)d_out;

    // ws layout (16B-aligned offsets)
    char* ws = (char*)d_ws;
    bf16*  xb      = (bf16*)ws;                                   // 2048*128*2     = 512 KB
    bf16*  aw      = (bf16*)(ws + 524288);                        // 100096*128*2   = 25.6 MB
    float* partial = (float*)(ws + 524288 + 25624576);            // 2048*782*4     = 6.4 MB
    float* contrib = (float*)(ws + 524288 + 25624576 + 6406144);  // 2048*4
    float* logits  = out + 1;                                     // d_out[0] = loss

    hipLaunchKernelGGL(k_cast_x, dim3(1024), dim3(256), 0, stream, x, xb, B_BATCH * D_DIM);
    hipLaunchKernelGGL(k_gather_aw, dim3(C_PAD / 2), dim3(256), 0, stream, w, pidx, aw);
    hipLaunchKernelGGL(k_gemm, dim3(16, NBLK_N), dim3(256), 0, stream, xb, aw, logits, partial);
    hipLaunchKernelGGL(k_row_reduce, dim3(B_BATCH), dim3(256), 0, stream, partial, logits, y, contrib);
    hipLaunchKernelGGL(k_loss, dim3(1), dim3(256), 0, stream, contrib, out);
}